// Round 1
// baseline (175.990 us; speedup 1.0000x reference)
//
#include <hip/hip_runtime.h>

typedef unsigned short ushort_t;
typedef unsigned int u32;
typedef short bf16x8 __attribute__((ext_vector_type(8)));
typedef float f32x4 __attribute__((ext_vector_type(4)));
typedef u32 u32x4 __attribute__((ext_vector_type(4)));

#define CCH 96
#define KTAPS 15
#define NBLK 192
#define ROWS 206          /* NBLK + 14 */
#define USTR 104          /* padded LDS row stride in ushorts (208 B, 16B-aligned) */
#define WSLAB_USH 9216    /* 96*96 */
#define WSLAB_B 18432
#define U_BYTES (ROWS*USTR*2)            /* 42848 */
#define LDS_BYTES (U_BYTES + 2*WSLAB_B)  /* 79712 */

__device__ __forceinline__ float bf2f(ushort_t u) {
    u32 x = ((u32)u) << 16;
    float f;
    __builtin_memcpy(&f, &x, 4);
    return f;
}
__device__ __forceinline__ ushort_t f2bf(float f) {
    u32 x;
    __builtin_memcpy(&x, &f, 4);
    x = x + 0x7fffu + ((x >> 16) & 1u);
    return (ushort_t)(x >> 16);
}

// ---------------- prep: fold unpool+mask into fragment-ordered bf16 weights ----
// Wf layout: [k][cblk(3)][mtile(6)][lane(64)][elem(8)] ushorts.
// lane = (o&15) | (((cc>>3)&3)<<4), elem = cc&7  (A-frag of mfma_f32_16x16x32_bf16)
__global__ void prep_w(const float* __restrict__ w, const float* __restrict__ mask,
                       ushort_t* __restrict__ Wf, int cpj)
{
    int idx = blockIdx.x * 256 + threadIdx.x;
    if (idx >= 96 * 96 * 15) return;
    int k = idx % 15;
    int cc = (idx / 15) % 96;
    int o = idx / (15 * 96);
    int i = cc / cpj, c = cc % cpj;
    float s = 0.f;
#pragma unroll
    for (int d = 0; d < 2; ++d) {
        int f = (2 * i + d) * cpj + c;
        s += w[(o * 192 + f) * 15 + k] * mask[(o * 192 + f) * 15 + k];
    }
    int lane = (o & 15) | (((cc >> 3) & 3) << 4);
    int pos = ((k * 3 + (cc >> 5)) * 6 + (o >> 4)) * 512 + lane * 8 + (cc & 7);
    Wf[pos] = f2bf(s);
}

// ADD[b][o] = conv_b[o] + (sum_j off_w[o,j]*off_mask[o,j]*offset[b,j] + off_b[o])/100
__global__ void prep_add(const float* __restrict__ offw, const float* __restrict__ offb,
                         const float* __restrict__ offmask, const float* __restrict__ convb,
                         const float* __restrict__ offsets, float* __restrict__ ADD, int J)
{
    int idx = blockIdx.x * 256 + threadIdx.x;
    if (idx >= 64 * 96) return;
    int o = idx % 96, b = idx / 96;
    float s = 0.f;
    for (int j = 0; j < J; ++j)
        s += offw[o * J + j] * offmask[o * J + j] * offsets[b * J + j];
    ADD[idx] = convb[o] + (s + offb[o]) * 0.01f;
}

__global__ void prep_x(const float* __restrict__ x, ushort_t* __restrict__ Xbf, int n)
{
    int i = (blockIdx.x * 256 + threadIdx.x) * 4;
    if (i >= n) return;
    float4 v = *(const float4*)(x + i);
    u32 lo = (u32)f2bf(v.x) | ((u32)f2bf(v.y) << 16);
    u32 hi = (u32)f2bf(v.z) | ((u32)f2bf(v.w) << 16);
    uint2 pk;
    pk.x = lo; pk.y = hi;
    *(uint2*)(Xbf + i) = pk;
}

// ---------------- fused upsample + folded masked conv1d (+bias/offset [+leaky]) --
// Uin: bf16 [B][T_in][96]. Output stage0: bf16 [B][2T][96]; stage1: f32 [B][96][2T-1].
#define GLDS(gsrc, ldst) __builtin_amdgcn_global_load_lds( \
    (const __attribute__((address_space(1))) u32*)(gsrc), \
    (__attribute__((address_space(3))) u32*)(ldst), 16, 0, 0)

template<int STAGE>
__launch_bounds__(256, 2)
__global__ void conv_fused(const ushort_t* __restrict__ Uin, const ushort_t* __restrict__ Wf,
                           const float* __restrict__ ADD, ushort_t* __restrict__ Hout,
                           float* __restrict__ Fout, int T_in)
{
    extern __shared__ char smem[];
    ushort_t* Ulds = (ushort_t*)smem;
    char* wlds = smem + U_BYTES;

    const int tid = threadIdx.x;
    const int lane = tid & 63;
    const int wid = tid >> 6;
    const int b = blockIdx.y;
    const int T2 = 2 * T_in;
    const int t_base = blockIdx.x * NBLK;

    // prefetch W slab k=0 into buffer 0 (overlaps U staging)
    {
        const char* src = (const char*)Wf;
        for (int i = wid; i < 18; i += 4)
            GLDS(src + i * 1024 + lane * 16, wlds + i * 1024);
    }

    // stage U tile with fused linear-x2 upsample (half-pixel, edge-normalized)
    const ushort_t* hb = Uin + (size_t)b * T_in * CCH;
    for (int idx = tid; idx < ROWS * 12; idx += 256) {
        int r = idx / 12;
        int q = idx - r * 12;
        int tp = t_base - 7 + r;
        u32x4 outv = (u32x4){0u, 0u, 0u, 0u};
        if (tp >= 0 && tp < T2) {
            int mm = tp >> 1;
            int p = tp & 1;
            int r0 = p ? mm : mm - 1;
            int r1 = p ? mm + 1 : mm;
            if (r0 < 0) r0 = 0;
            if (r1 > T_in - 1) r1 = T_in - 1;
            float w0 = p ? 0.75f : 0.25f;
            float w1 = 1.0f - w0;
            u32x4 av = *(const u32x4*)(hb + r0 * CCH + q * 8);
            u32x4 cv = *(const u32x4*)(hb + r1 * CCH + q * 8);
#pragma unroll
            for (int e = 0; e < 4; ++e) {
                u32 aa = av[e], cc2 = cv[e];
                float lo = w0 * bf2f((ushort_t)(aa & 0xffffu)) + w1 * bf2f((ushort_t)(cc2 & 0xffffu));
                float hi = w0 * bf2f((ushort_t)(aa >> 16)) + w1 * bf2f((ushort_t)(cc2 >> 16));
                outv[e] = (u32)f2bf(lo) | ((u32)f2bf(hi) << 16);
            }
        }
        *(u32x4*)(Ulds + r * USTR + q * 8) = outv;
    }
    __syncthreads();

    f32x4 acc[6][3];
#pragma unroll
    for (int m2 = 0; m2 < 6; ++m2)
#pragma unroll
        for (int n = 0; n < 3; ++n) acc[m2][n] = (f32x4){0.f, 0.f, 0.f, 0.f};

    const int colbase = (lane >> 4) * 8;
    const int rowbase = 48 * wid + (lane & 15);

    for (int k = 0; k < KTAPS; ++k) {
        if (k + 1 < KTAPS) {  // prefetch next tap's weight slab into other buffer
            const char* src = (const char*)(Wf + (size_t)(k + 1) * WSLAB_USH);
            char* dst = wlds + ((k + 1) & 1) * WSLAB_B;
            for (int i = wid; i < 18; i += 4)
                GLDS(src + i * 1024 + lane * 16, dst + i * 1024);
        }
        const ushort_t* wb = (const ushort_t*)(wlds + (k & 1) * WSLAB_B);
#pragma unroll
        for (int cb = 0; cb < 3; ++cb) {
            bf16x8 bfr[3];
#pragma unroll
            for (int n = 0; n < 3; ++n)
                bfr[n] = *(const bf16x8*)(Ulds + (rowbase + n * 16 + k) * USTR + cb * 32 + colbase);
            bf16x8 afr[6];
#pragma unroll
            for (int m2 = 0; m2 < 6; ++m2)
                afr[m2] = *(const bf16x8*)(wb + (cb * 6 + m2) * 512 + lane * 8);
#pragma unroll
            for (int m2 = 0; m2 < 6; ++m2)
#pragma unroll
                for (int n = 0; n < 3; ++n)
                    acc[m2][n] = __builtin_amdgcn_mfma_f32_16x16x32_bf16(afr[m2], bfr[n], acc[m2][n], 0, 0, 0);
        }
        __syncthreads();  // drains vmcnt -> next slab resident; protects dbuf reuse
    }

    // epilogue: D-frag (o = m*16 + (lane>>4)*4 + rr, t = t_base + 48*wid + n*16 + (lane&15))
    const int og = (lane >> 4) * 4;
#pragma unroll
    for (int m2 = 0; m2 < 6; ++m2) {
        const int o0 = m2 * 16 + og;
        float addv[4];
#pragma unroll
        for (int rr = 0; rr < 4; ++rr) addv[rr] = ADD[b * 96 + o0 + rr];
#pragma unroll
        for (int n = 0; n < 3; ++n) {
            int t = t_base + 48 * wid + n * 16 + (lane & 15);
            if (STAGE == 0) {
                if (t < T2) {
                    ushort_t pk[4];
#pragma unroll
                    for (int rr = 0; rr < 4; ++rr) {
                        float v = acc[m2][n][rr] + addv[rr];
                        v = v > 0.f ? v : 0.2f * v;
                        pk[rr] = f2bf(v);
                    }
                    uint2 st;
                    st.x = (u32)pk[0] | ((u32)pk[1] << 16);
                    st.y = (u32)pk[2] | ((u32)pk[3] << 16);
                    *(uint2*)(Hout + ((size_t)b * T2 + t) * CCH + o0) = st;
                }
            } else {
                const int TO = T2 - 1;  // trimmed output length (4095)
                if (t < TO) {
#pragma unroll
                    for (int rr = 0; rr < 4; ++rr)
                        Fout[((size_t)(b * 96 + o0 + rr)) * TO + t] = acc[m2][n][rr] + addv[rr];
                }
            }
        }
    }
}

extern "C" void kernel_launch(void* const* d_in, const int* in_sizes, int n_in,
                              void* d_out, int out_size, void* d_ws, size_t ws_size,
                              hipStream_t stream)
{
    const float* x       = (const float*)d_in[0];
    const float* offset0 = (const float*)d_in[1];
    const float* offset1 = (const float*)d_in[2];
    const float* conv_w0 = (const float*)d_in[5];
    const float* conv_b0 = (const float*)d_in[6];
    const float* conv_w1 = (const float*)d_in[7];
    const float* conv_b1 = (const float*)d_in[8];
    const float* off_w0  = (const float*)d_in[9];
    const float* off_b0  = (const float*)d_in[10];
    const float* off_w1  = (const float*)d_in[11];
    const float* off_b1  = (const float*)d_in[12];
    const float* cmask0  = (const float*)d_in[13];
    const float* cmask1  = (const float*)d_in[14];
    const float* omask0  = (const float*)d_in[15];
    const float* omask1  = (const float*)d_in[16];

    char* ws = (char*)d_ws;
    ushort_t* Wf0 = (ushort_t*)(ws);                 // 276480 B
    ushort_t* Wf1 = (ushort_t*)(ws + 276480);        // 276480 B
    float* ADD0   = (float*)(ws + 552960);           // 24576 B
    float* ADD1   = (float*)(ws + 577536);           // 24576 B
    ushort_t* Xbf = (ushort_t*)(ws + 602112);        // 12582912 B (bf16 x)
    ushort_t* H1  = (ushort_t*)(ws + 13185024);      // 25165824 B (stage0 out bf16)
    float* out    = (float*)d_out;

    prep_w<<<540, 256, 0, stream>>>(conv_w0, cmask0, Wf0, 16);
    prep_w<<<540, 256, 0, stream>>>(conv_w1, cmask1, Wf1, 8);
    prep_add<<<24, 256, 0, stream>>>(off_w0, off_b0, omask0, conv_b0, offset0, ADD0, 36);
    prep_add<<<24, 256, 0, stream>>>(off_w1, off_b1, omask1, conv_b1, offset1, ADD1, 72);
    prep_x<<<6144, 256, 0, stream>>>(x, Xbf, 64 * 1024 * 96);

    (void)hipFuncSetAttribute(reinterpret_cast<const void*>(&conv_fused<0>),
                              hipFuncAttributeMaxDynamicSharedMemorySize, LDS_BYTES);
    (void)hipFuncSetAttribute(reinterpret_cast<const void*>(&conv_fused<1>),
                              hipFuncAttributeMaxDynamicSharedMemorySize, LDS_BYTES);

    conv_fused<0><<<dim3(11, 64), 256, LDS_BYTES, stream>>>(Xbf, Wf0, ADD0, H1, nullptr, 1024);
    conv_fused<1><<<dim3(22, 64), 256, LDS_BYTES, stream>>>(H1, Wf1, ADD1, nullptr, out, 2048);
}

// Round 2
// 169.781 us; speedup vs baseline: 1.0366x; 1.0366x over previous
//
#include <hip/hip_runtime.h>

typedef unsigned short ushort_t;
typedef unsigned int u32;
typedef short bf16x8 __attribute__((ext_vector_type(8)));
typedef float f32x4 __attribute__((ext_vector_type(4)));
typedef u32 u32x4 __attribute__((ext_vector_type(4)));

__device__ __forceinline__ float bf2f(ushort_t u) {
    u32 x = ((u32)u) << 16; float f; __builtin_memcpy(&f, &x, 4); return f;
}
__device__ __forceinline__ ushort_t f2bf(float f) {
    u32 x; __builtin_memcpy(&x, &f, 4);
    x = x + 0x7fffu + ((x >> 16) & 1u);
    return (ushort_t)(x >> 16);
}

#define GLDS(gsrc, ldst) __builtin_amdgcn_global_load_lds( \
    (const __attribute__((address_space(1))) u32*)(gsrc), \
    (__attribute__((address_space(3))) u32*)(ldst), 16, 0, 0)

#define NBB 192                       /* base rows per block */
#define UROWS 200                     /* NBB + 8 halo */
#define USTRB 208                     /* bytes per U row (96 bf16 + pad), 16B mult */
#define UB_BYTES (UROWS * USTRB)      /* 41600 */
#define SLAB_B 36864                  /* per-tap weight slab, both phases */
#define LDS_TOTAL (UB_BYTES + 3 * SLAB_B) /* 152192 <= 160K */

// ---------- prep 1: fold unpool+mask -> Wplain f32 [stage][o][cc][k] ----------
__global__ void prep_fold(const float* __restrict__ w0, const float* __restrict__ m0,
                          const float* __restrict__ w1, const float* __restrict__ m1,
                          float* __restrict__ Wplain)
{
    int idx = blockIdx.x * 256 + threadIdx.x;
    if (idx >= 2 * 96 * 96 * 15) return;
    int k = idx % 15;
    int cc = (idx / 15) % 96;
    int o = (idx / (15 * 96)) % 96;
    int st = idx / (15 * 96 * 96);
    const float* w = st ? w1 : w0;
    const float* mk = st ? m1 : m0;
    int cpj = st ? 8 : 16;
    int i = cc / cpj, c = cc % cpj;
    float s = 0.f;
#pragma unroll
    for (int d = 0; d < 2; ++d) {
        int f = (2 * i + d) * cpj + c;
        s += w[(o * 192 + f) * 15 + k] * mk[(o * 192 + f) * 15 + k];
    }
    Wplain[idx] = s;
}

// ---------- prep 2: polyphase weights (frag layout) + G0 + ADD0/ADD1 ----------
// Wp layout: [(j*2+p)*18 + cb*6 + m2]*512 + lane*8 + e  (A-frag of 16x16x32 bf16)
__global__ void prep_k2(const float* __restrict__ Wplain, const float* __restrict__ x,
                        const float* __restrict__ offw0, const float* __restrict__ offb0,
                        const float* __restrict__ omask0, const float* __restrict__ convb0,
                        const float* __restrict__ off0,
                        const float* __restrict__ offw1, const float* __restrict__ offb1,
                        const float* __restrict__ omask1, const float* __restrict__ convb1,
                        const float* __restrict__ off1,
                        ushort_t* __restrict__ Wp0, ushort_t* __restrict__ Wp1,
                        float* __restrict__ G0, float* __restrict__ ADD0, float* __restrict__ ADD1)
{
    int idx = blockIdx.x * 256 + threadIdx.x;
    if (idx < 331776) {                       // 2st x 2p x 9j x 96o x 96cc
        int cc = idx % 96; int t = idx / 96;
        int o = t % 96; t /= 96;
        int j = t % 9; t /= 9;
        int p = t % 2; int st = t / 2;
        const float* WP = Wplain + (size_t)st * 96 * 96 * 15;
        int kk[4]; float cf[4];
        if (p == 0) { kk[0]=2*j;   cf[0]=0.75f; kk[1]=2*j-2; cf[1]=0.25f;
                      kk[2]=2*j+1; cf[2]=0.25f; kk[3]=2*j-1; cf[3]=0.75f; }
        else        { kk[0]=2*j;   cf[0]=0.25f; kk[1]=2*j-2; cf[1]=0.75f;
                      kk[2]=2*j-1; cf[2]=0.75f; kk[3]=2*j-3; cf[3]=0.25f; }
        float s = 0.f;
#pragma unroll
        for (int q = 0; q < 4; ++q) {
            int k = kk[q];
            if (k >= 0 && k < 15) s += cf[q] * WP[((size_t)o * 96 + cc) * 15 + k];
        }
        int lane = (o & 15) | (((cc >> 3) & 3) << 4);
        int pos = ((j * 2 + p) * 18 + (cc >> 5) * 6 + (o >> 4)) * 512 + lane * 8 + (cc & 7);
        (st ? Wp1 : Wp0)[pos] = f2bf(s);
    } else if (idx < 331776 + 184320) {       // G0: 64b x 96o x 15k x 2side
        int g = idx - 331776;
        int side = g % 2; g /= 2;
        int k = g % 15; g /= 15;
        int o = g % 96; int b = g / 96;
        int row = side ? 1023 : 0;
        const float* xr = x + ((size_t)b * 1024 + row) * 96;
        const float* WP = Wplain + (size_t)o * 96 * 15;
        float s = 0.f;
        for (int cc = 0; cc < 96; ++cc)
            s += WP[cc * 15 + k] * bf2f(f2bf(xr[cc]));
        G0[(((size_t)(b * 96 + o) * 15) + k) * 2 + side] = s;
    } else if (idx < 331776 + 184320 + 12288) { // ADD both stages: 2 x 64 x 96
        int a = idx - 516096;
        int st = a / 6144; int a2 = a % 6144;
        int o = a2 % 96, b = a2 / 96;
        const float* ow = st ? offw1 : offw0;
        const float* ob = st ? offb1 : offb0;
        const float* om = st ? omask1 : omask0;
        const float* cb = st ? convb1 : convb0;
        const float* of = st ? off1 : off0;
        int J = st ? 72 : 36;
        float s = 0.f;
        for (int j2 = 0; j2 < J; ++j2) s += ow[o * J + j2] * om[o * J + j2] * of[b * J + j2];
        (st ? ADD1 : ADD0)[b * 96 + o] = cb[o] + (s + ob[o]) * 0.01f;
    }
}

// ---------- G for stage1 (needs H1) ----------
__global__ void prep_G1(const float* __restrict__ WPst, const ushort_t* __restrict__ H1,
                        float* __restrict__ G, int T)
{
    int idx = blockIdx.x * 256 + threadIdx.x;
    if (idx >= 184320) return;
    int side = idx % 2; int g = idx / 2;
    int k = g % 15; g /= 15;
    int o = g % 96; int b = g / 96;
    int row = side ? T - 1 : 0;
    const ushort_t* hr = H1 + ((size_t)b * T + row) * 96;
    float s = 0.f;
    for (int cc = 0; cc < 96; ++cc)
        s += WPst[((size_t)o * 96 + cc) * 15 + k] * bf2f(hr[cc]);
    G[(((size_t)(b * 96 + o) * 15) + k) * 2 + side] = s;
}

// ---------- CF/CB boundary tables from G ----------
__global__ void prep_cfb(const float* __restrict__ G, float* __restrict__ CF, float* __restrict__ CB)
{
    int idx = blockIdx.x * 256 + threadIdx.x;
    if (idx >= 86016) return;                 // 64 x 96 x 14
    int seg = idx % 14; int r = idx / 14;
    int o = r % 96; int b = r / 96;
    bool front = seg < 7; int t = front ? seg : seg - 7;
    float s = 0.f;
    if (front) { for (int k = 0; k <= 6 - t; ++k)  s += G[(((size_t)(b*96+o)*15)+k)*2 + 0]; }
    else       { for (int k = 14 - t; k <= 14; ++k) s += G[(((size_t)(b*96+o)*15)+k)*2 + 1]; }
    (front ? CF : CB)[(b * 7 + t) * 96 + o] = s;
}

// ---------- fused polyphase conv: both phases per block, 8 waves ----------
template<int STAGE>
__launch_bounds__(512, 2)
__global__ void conv_poly(const float* __restrict__ Xf, const ushort_t* __restrict__ Hbf,
                          const ushort_t* __restrict__ Wp, const float* __restrict__ ADD,
                          const float* __restrict__ CF, const float* __restrict__ CB,
                          ushort_t* __restrict__ Hout, float* __restrict__ Fout, int T)
{
    extern __shared__ char smem[];
    char* Ub = smem;
    char* wlds = smem + UB_BYTES;

    const int tid = threadIdx.x;
    const int lane = tid & 63;
    const int wid = tid >> 6;
    const int b = blockIdx.y;
    const int tg = blockIdx.x;
    const int phase = wid & 1;
    const int nq = wid >> 1;          // n-quarter: 48 base rows each
    const int rb0 = tg * NBB - 4;

    const char* wsrc = (const char*)Wp;
    // prefetch slab 0 (waves 0..3, 9 GLDS each)
    if (wid < 4)
        for (int i = wid; i < 36; i += 4)
            GLDS(wsrc + i * 1024 + lane * 16, wlds + i * 1024);

    // stage U at base rate, clamped rows, (r&8)<<1 XOR swizzle on 16B granules
    if (STAGE == 0) {
        const float* xb = Xf + (size_t)b * T * 96;
        for (int idx = tid; idx < UROWS * 12; idx += 512) {
            int r = idx / 12, q = idx - r * 12;
            int rg = rb0 + r; rg = rg < 0 ? 0 : (rg > T - 1 ? T - 1 : rg);
            const float* src = xb + (size_t)rg * 96 + q * 8;
            float4 a = *(const float4*)src;
            float4 c2 = *(const float4*)(src + 4);
            u32x4 v;
            v[0] = (u32)f2bf(a.x) | ((u32)f2bf(a.y) << 16);
            v[1] = (u32)f2bf(a.z) | ((u32)f2bf(a.w) << 16);
            v[2] = (u32)f2bf(c2.x) | ((u32)f2bf(c2.y) << 16);
            v[3] = (u32)f2bf(c2.z) | ((u32)f2bf(c2.w) << 16);
            int off = r * USTRB + q * 16; off ^= (r & 8) << 1;
            *(u32x4*)(Ub + off) = v;
        }
    } else {
        const ushort_t* xb = Hbf + (size_t)b * T * 96;
        for (int idx = tid; idx < UROWS * 12; idx += 512) {
            int r = idx / 12, q = idx - r * 12;
            int rg = rb0 + r; rg = rg < 0 ? 0 : (rg > T - 1 ? T - 1 : rg);
            u32x4 v = *(const u32x4*)(xb + (size_t)rg * 96 + q * 8);
            int off = r * USTRB + q * 16; off ^= (r & 8) << 1;
            *(u32x4*)(Ub + off) = v;
        }
    }
    // prefetch slab 1
    if (wid < 4)
        for (int i = wid; i < 36; i += 4)
            GLDS(wsrc + SLAB_B + i * 1024 + lane * 16, wlds + SLAB_B + i * 1024);
    __syncthreads();   // full drain once: slabs 0,1 resident, U visible

    f32x4 acc[6][3];
#pragma unroll
    for (int m2 = 0; m2 < 6; ++m2)
#pragma unroll
        for (int n = 0; n < 3; ++n) acc[m2][n] = (f32x4){0.f, 0.f, 0.f, 0.f};

    const int rowbase = 48 * nq + (lane & 15);
    const int og16 = (lane >> 4) * 16;

    for (int j = 0; j < 9; ++j) {
        // counted wait: own outstanding <= 9 (the j+1 slab) => slab j landed
        if (wid < 4) asm volatile("s_waitcnt vmcnt(9)" ::: "memory");
        __builtin_amdgcn_s_barrier();
        __builtin_amdgcn_sched_barrier(0);
        if (j + 2 <= 8 && wid < 4) {
            const char* src = wsrc + (size_t)(j + 2) * SLAB_B;
            char* dst2 = wlds + ((j + 2) % 3) * SLAB_B;
            for (int i = wid; i < 36; i += 4)
                GLDS(src + i * 1024 + lane * 16, dst2 + i * 1024);
        }
        const ushort_t* wb = (const ushort_t*)(wlds + (j % 3) * SLAB_B) + phase * 9216;
#pragma unroll
        for (int cb = 0; cb < 3; ++cb) {
            bf16x8 bfr[3];
#pragma unroll
            for (int n = 0; n < 3; ++n) {
                int row = rowbase + n * 16 + j;
                int off = row * USTRB + cb * 64 + og16; off ^= (row & 8) << 1;
                bfr[n] = *(const bf16x8*)(Ub + off);
            }
            bf16x8 afr[6];
#pragma unroll
            for (int m2 = 0; m2 < 6; ++m2)
                afr[m2] = *(const bf16x8*)(wb + (cb * 6 + m2) * 512 + lane * 8);
#pragma unroll
            for (int m2 = 0; m2 < 6; ++m2)
#pragma unroll
                for (int n = 0; n < 3; ++n)
                    acc[m2][n] = __builtin_amdgcn_mfma_f32_16x16x32_bf16(afr[m2], bfr[n], acc[m2][n], 0, 0, 0);
        }
    }

    // epilogue
    const int T2 = 2 * T;
    const int og = (lane >> 4) * 4;
#pragma unroll
    for (int m2 = 0; m2 < 6; ++m2) {
        int o0 = m2 * 16 + og;
        float addv[4];
#pragma unroll
        for (int rr = 0; rr < 4; ++rr) addv[rr] = ADD[b * 96 + o0 + rr];
#pragma unroll
        for (int n = 0; n < 3; ++n) {
            int mloc = rowbase + n * 16;
            int mg = tg * NBB + mloc;
            if (mg >= T) continue;
            int t = 2 * mg + phase;
            float v4[4];
#pragma unroll
            for (int rr = 0; rr < 4; ++rr) {
                float v = acc[m2][n][rr] + addv[rr];
                if (t < 7)       v -= CF[(b * 7 + t) * 96 + o0 + rr];
                if (t >= T2 - 7) v -= CB[(b * 7 + (t - (T2 - 7))) * 96 + o0 + rr];
                if (STAGE == 0)  v = v > 0.f ? v : 0.2f * v;
                v4[rr] = v;
            }
            if (STAGE == 0) {
                uint2 st;
                st.x = (u32)f2bf(v4[0]) | ((u32)f2bf(v4[1]) << 16);
                st.y = (u32)f2bf(v4[2]) | ((u32)f2bf(v4[3]) << 16);
                *(uint2*)(Hout + ((size_t)b * T2 + t) * 96 + o0) = st;
            } else {
                if (t < T2 - 1) {
#pragma unroll
                    for (int rr = 0; rr < 4; ++rr)
                        Fout[((size_t)(b * 96 + o0 + rr)) * (T2 - 1) + t] = v4[rr];
                }
            }
        }
    }
}

extern "C" void kernel_launch(void* const* d_in, const int* in_sizes, int n_in,
                              void* d_out, int out_size, void* d_ws, size_t ws_size,
                              hipStream_t stream)
{
    const float* x       = (const float*)d_in[0];
    const float* offset0 = (const float*)d_in[1];
    const float* offset1 = (const float*)d_in[2];
    const float* conv_w0 = (const float*)d_in[5];
    const float* conv_b0 = (const float*)d_in[6];
    const float* conv_w1 = (const float*)d_in[7];
    const float* conv_b1 = (const float*)d_in[8];
    const float* off_w0  = (const float*)d_in[9];
    const float* off_b0  = (const float*)d_in[10];
    const float* off_w1  = (const float*)d_in[11];
    const float* off_b1  = (const float*)d_in[12];
    const float* cmask0  = (const float*)d_in[13];
    const float* cmask1  = (const float*)d_in[14];
    const float* omask0  = (const float*)d_in[15];
    const float* omask1  = (const float*)d_in[16];

    char* ws = (char*)d_ws;
    float*    Wplain = (float*)(ws);                  // 1,105,920
    ushort_t* Wp0    = (ushort_t*)(ws + 1105920);     // 331,776
    ushort_t* Wp1    = (ushort_t*)(ws + 1437696);     // 331,776
    float*    ADD0   = (float*)(ws + 1769472);        // 24,576
    float*    ADD1   = (float*)(ws + 1794048);        // 24,576
    float*    G0     = (float*)(ws + 1818624);        // 737,280
    float*    G1     = (float*)(ws + 2555904);        // 737,280
    float*    CF0    = (float*)(ws + 3293184);        // 172,032
    float*    CB0    = (float*)(ws + 3465216);        // 172,032
    float*    CF1    = (float*)(ws + 3637248);        // 172,032
    float*    CB1    = (float*)(ws + 3809280);        // 172,032
    ushort_t* H1     = (ushort_t*)(ws + 3981312);     // 25,165,824
    float* out = (float*)d_out;

    prep_fold<<<1080, 256, 0, stream>>>(conv_w0, cmask0, conv_w1, cmask1, Wplain);
    prep_k2<<<2064, 256, 0, stream>>>(Wplain, x,
                                      off_w0, off_b0, omask0, conv_b0, offset0,
                                      off_w1, off_b1, omask1, conv_b1, offset1,
                                      Wp0, Wp1, G0, ADD0, ADD1);
    prep_cfb<<<336, 256, 0, stream>>>(G0, CF0, CB0);

    (void)hipFuncSetAttribute(reinterpret_cast<const void*>(&conv_poly<0>),
                              hipFuncAttributeMaxDynamicSharedMemorySize, LDS_TOTAL);
    (void)hipFuncSetAttribute(reinterpret_cast<const void*>(&conv_poly<1>),
                              hipFuncAttributeMaxDynamicSharedMemorySize, LDS_TOTAL);

    conv_poly<0><<<dim3(6, 64), 512, LDS_TOTAL, stream>>>(x, nullptr, Wp0, ADD0, CF0, CB0,
                                                          H1, nullptr, 1024);
    prep_G1<<<720, 256, 0, stream>>>(Wplain + (size_t)96 * 96 * 15, H1, G1, 2048);
    prep_cfb<<<336, 256, 0, stream>>>(G1, CF1, CB1);
    conv_poly<1><<<dim3(11, 64), 512, LDS_TOTAL, stream>>>(nullptr, H1, Wp1, ADD1, CF1, CB1,
                                                           nullptr, out, 2048);
}